// Round 8
// baseline (324.025 us; speedup 1.0000x reference)
//
#include <hip/hip_runtime.h>
#include <cstdint>
#include <cstddef>

#define N_NODES 8192
#define IN_DIM 128
#define H 32
#define KB 8192
#define NCH 66
#define NB 512            // grid blocks (2/CU on 256 CUs)
#define BT 512            // threads/block

typedef __attribute__((ext_vector_type(8))) short short8;
typedef __attribute__((ext_vector_type(4))) float f32x4;

__device__ __forceinline__ float sigmoidf_(float x) { return 1.0f / (1.0f + __expf(-x)); }
__device__ __forceinline__ float tanh_fast(float x) { return 1.0f - 2.0f / (1.0f + __expf(2.0f * x)); }
__device__ __forceinline__ unsigned short f2bf(float f) {
    unsigned u = __float_as_uint(f);
    unsigned r = (u + 0x7fffu + ((u >> 16) & 1u)) >> 16;
    return (unsigned short)r;
}
__device__ __forceinline__ unsigned pack_bf_pair(float lo, float hi) {
    unsigned a = __float_as_uint(lo) + 0x7FFFu;
    unsigned b = __float_as_uint(hi) + 0x7FFFu;
    return __builtin_amdgcn_perm(b, a, 0x07060302u);
}

// monotonic device-wide barrier: all NB blocks co-resident (enforced by
// launch_bounds + 33.5KB LDS => 2 blocks/CU). cnt zeroed by hipMemsetAsync.
__device__ __forceinline__ void gsync(unsigned* cnt, unsigned target) {
    __syncthreads();
    if (threadIdx.x == 0) {
        __threadfence();
        atomicAdd(cnt, 1u);
        while (atomicAdd(cnt, 0u) < target) { __builtin_amdgcn_s_sleep(2); }
        __threadfence();
    }
    __syncthreads();
}

__global__ __launch_bounds__(BT, 4) void han_mega(
    const float* __restrict__ x,
    const float* __restrict__ W1, const float* __restrict__ b1, const float* __restrict__ a1,
    const float* __restrict__ W2, const float* __restrict__ b2, const float* __restrict__ a2,
    const float* __restrict__ q,  const float* __restrict__ Wsw, const float* __restrict__ Wsb,
    const float* __restrict__ bsem, const float* __restrict__ clsw, const float* __restrict__ clsb,
    const int* __restrict__ adj,
    unsigned* cnt, unsigned short* WhTf, float* s1g,
    float* maxp1, float* maxp2, float* minp2, float* wsum,
    float* num1, float* den1, float* Sc, float* out)
{
    __shared__ __align__(16) char smem[33536];
    int tid = threadIdx.x;
    int b   = blockIdx.x;
    int r   = tid >> 5;          // 0..15 (row within block's 16-row slab)
    int h   = tid & 31;
    int lane = tid & 63;
    int wv  = tid >> 6;          // wave 0..7

    // ================= Phase A: k1 (Wh, s, partial max) + zero Sc/wsum =====
    {
        int base = b * 1056;     // 540672/512
        Sc[base + tid] = 0.f;
        Sc[base + 512 + tid] = 0.f;
        if (tid < 32) Sc[base + 1024 + tid] = 0.f;
        if (b == 0 && tid < 2) wsum[tid] = 0.f;
    }
    float* xl = (float*)smem;                 // 16*128 f = 8KB
    float* redA = (float*)(smem + 8192);      // 24 f
    int r0 = b * 16;
    ((float4*)xl)[tid] = ((const float4*)(x + (size_t)r0 * IN_DIM))[tid];
    __syncthreads();

    float wh2, sv2, z1v, z2v, m0, m1, lo, invw;  // live across phases
    {
        const float* xr  = xl + r * IN_DIM;
        const float* w1r = W1 + h * IN_DIM;
        const float* w2r = W2 + h * IN_DIM;
        float d1 = 0.f, d2 = 0.f;
#pragma unroll 8
        for (int k = 0; k < IN_DIM; k += 4) {
            float4 xv = *(const float4*)(xr + k);
            float4 wa = *(const float4*)(w1r + k);
            float4 wb = *(const float4*)(w2r + k);
            d1 += xv.x * wa.x + xv.y * wa.y + xv.z * wa.z + xv.w * wa.w;
            d2 += xv.x * wb.x + xv.y * wb.y + xv.z * wb.z + xv.w * wb.w;
        }
        int grow = r0 + r;
        float wh1 = d1 + b1[h];
        wh2 = d2 + b2[h];
        // fragment-layout scatter store of bf16 Wh1 (same mapping as round 7)
        {
            int T  = grow >> 7;
            int kk = grow & 127;
            int ks = kk >> 5;
            int kg = (kk >> 3) & 3;
            int e  = kk & 7;
            int ln = (h & 15) | (kg << 4);
            size_t off = ((size_t)((T * 2 + (h >> 4)) * 4 + ks) << 9) + (size_t)ln * 8 + e;
            WhTf[off] = f2bf(wh1);
        }
        float v1 = wh1 * a1[h];
        float v2 = wh2 * a2[h];
#pragma unroll
        for (int m = 16; m >= 1; m >>= 1) { v1 += __shfl_xor(v1, m); v2 += __shfl_xor(v2, m); }
        sv2 = v2;                               // row's s2, uniform in 32-group
        if (h == 0) s1g[grow] = v1;
        // block-level max/min partials
        float bm1 = fmaxf(v1, __shfl_xor(v1, 32));
        float bm2 = fmaxf(v2, __shfl_xor(v2, 32));
        float bn2 = fminf(v2, __shfl_xor(v2, 32));
        if (lane == 0) { redA[wv * 3] = bm1; redA[wv * 3 + 1] = bm2; redA[wv * 3 + 2] = bn2; }
        __syncthreads();
        if (tid == 0) {
            float a_ = redA[0], b_ = redA[1], c_ = redA[2];
            for (int w = 1; w < 8; ++w) {
                a_ = fmaxf(a_, redA[w * 3]);
                b_ = fmaxf(b_, redA[w * 3 + 1]);
                c_ = fminf(c_, redA[w * 3 + 2]);
            }
            maxp1[b] = a_; maxp2[b] = b_; minp2[b] = c_;
        }
    }
    gsync(cnt, NB);

    // ================= Phase B: global max/min (redundant per block) =======
    {
        float* redB = (float*)smem;           // 24 f
        float t1 = maxp1[tid], t2 = maxp2[tid], t3 = minp2[tid];
#pragma unroll
        for (int m = 32; m >= 1; m >>= 1) {
            t1 = fmaxf(t1, __shfl_xor(t1, m));
            t2 = fmaxf(t2, __shfl_xor(t2, m));
            t3 = fminf(t3, __shfl_xor(t3, m));
        }
        if (lane == 0) { redB[wv * 3] = t1; redB[wv * 3 + 1] = t2; redB[wv * 3 + 2] = t3; }
        __syncthreads();
        m0 = redB[0]; m1 = redB[1]; lo = redB[2];
        for (int w = 1; w < 8; ++w) {
            m0 = fmaxf(m0, redB[w * 3]);
            m1 = fmaxf(m1, redB[w * 3 + 1]);
            lo = fminf(lo, redB[w * 3 + 2]);
        }
        invw = (float)KB / fmaxf(m1 - lo, 1e-9f);
    }

    // ================= Phase C: path-2 bucket atomics (from registers) =====
    {
        int bi = (int)((sv2 - lo) * invw);
        bi = min(max(bi, 0), KB - 1);
        float E = __expf(sv2 - m1);
        float F = __expf(0.2f * (sv2 - m1));
        atomicAdd(&Sc[(size_t)h * KB + bi], E * wh2);
        atomicAdd(&Sc[(size_t)(32 + h) * KB + bi], F * wh2);
        if (h == 0) {
            atomicAdd(&Sc[(size_t)64 * KB + bi], E);
            atomicAdd(&Sc[(size_t)65 * KB + bi], F);
        }
    }
    gsync(cnt, 2 * NB);

    // ================= Phase D: suffix scan (blocks 0..65) then k2 (all) ===
    if (b < NCH) {
        float* chb = Sc + (size_t)b * KB;
        float* wtp = (float*)smem;            // 8 f
        float* carryp = (float*)(smem + 64);
        float carry = 0.f;
        for (int chunk = 7; chunk >= 0; --chunk) {
            float* base = chb + chunk * 1024;
            int k0 = tid * 2;
            float x0 = base[1023 - k0];
            float x1 = base[1022 - k0];
            float p1 = x0 + x1;
            float inc = p1;
#pragma unroll
            for (int d = 1; d < 64; d <<= 1) {
                float y = __shfl_up(inc, d);
                if (lane >= d) inc += y;
            }
            if (lane == 63) wtp[wv] = inc;
            __syncthreads();
            float woff = carry;
            for (int wi = 0; wi < 8; ++wi) if (wi < wv) woff += wtp[wi];
            float offv = woff + (inc - p1);
            base[1023 - k0] = x0 + offv;
            base[1022 - k0] = p1 + offv;
            if (tid == BT - 1) *carryp = p1 + offv;
            __syncthreads();
            carry = *carryp;
        }
    }

    // ---- k2: path-1 MFMA attention (round-7 structure) ----
    f32x4 acc1 = {0.f, 0.f, 0.f, 0.f};
    float l0 = 0.f, l1 = 0.f, l2 = 0.f, l3 = 0.f;
    int rowblk = b >> 2;
    int jb = b & 3;
    int row0 = rowblk * 64;
    int jstart = jb * 2048;
    {
        unsigned short* wA = (unsigned short*)smem;            // 16 KB
        unsigned short* wB = (unsigned short*)(smem + 16384);  // 16 KB
        float* srow = (float*)(smem + 32768);                  // 64 f
        float* g1r  = (float*)(smem + 33024);
        float* g2r  = (float*)(smem + 33280);

        __syncthreads();   // smem handoff (scan wtp region -> k2 regions)
        if (tid < 64) {
            float sv = s1g[row0 + tid];
            srow[tid] = sv;
            float u = sv + m0;
            g1r[tid] = u >= 0.f ? 1.f : __expf(0.8f * u);
            g2r[tid] = u >= 0.f ? __expf(-0.8f * u) : 1.f;
        }
        __syncthreads();

        int rg = wv >> 1;
        int hg = wv & 1;
        int grp = lane >> 4;
        int arow = rg * 16 + (lane & 15);
        int aswz = (arow & 7) << 4;
        int a_base = arow * 256;
        const unsigned short* bf_base = WhTf + (size_t)lane * 8 + (size_t)hg * 2048;
        int tcol = (tid & 31) * 4;
        int trh = tid >> 5;
        const int* adjb = adj + (size_t)row0 * N_NODES + tcol;

        int4 cA, cB, cC, cD, nA, nB_, nC, nD;
        short8 Bc0, Bc1, Bc2, Bc3, Bn0, Bn1, Bn2, Bn3;
        float4 sj, e4, f4;

#define W_GEN(KK, AV, LL, WB)                                                   \
        {                                                                       \
            int rr = KK * 16 + trh;                                             \
            float sr = srow[rr], g1v = g1r[rr], g2v = g2r[rr];                  \
            bool px = sr + sj.x >= 0.f, py = sr + sj.y >= 0.f;                  \
            bool pz = sr + sj.z >= 0.f, pw = sr + sj.w >= 0.f;                  \
            float wx = (px ? g1v : g2v) * (px ? e4.x : f4.x);                   \
            float wy = (py ? g1v : g2v) * (py ? e4.y : f4.y);                   \
            float wz = (pz ? g1v : g2v) * (pz ? e4.z : f4.z);                   \
            float ww = (pw ? g1v : g2v) * (pw ? e4.w : f4.w);                   \
            if (AV.x == 0) wx = 0.f;                                            \
            if (AV.y == 0) wy = 0.f;                                            \
            if (AV.z == 0) wz = 0.f;                                            \
            if (AV.w == 0) ww = 0.f;                                            \
            LL += (wx + wy) + (wz + ww);                                        \
            uint2 pk;                                                           \
            pk.x = pack_bf_pair(wx, wy);                                        \
            pk.y = pack_bf_pair(wz, ww);                                        \
            int byte = (rr * 256 + tcol * 2) ^ ((rr & 7) << 4);                 \
            *(uint2*)((char*)(WB) + byte) = pk;                                 \
        }
#define SJ_LOAD(J0)  sj = *(const float4*)(s1g + (J0) + tcol);
#define EF_GEN()                                                                \
        {                                                                       \
            e4.x = __expf(sj.x - m0); e4.y = __expf(sj.y - m0);                 \
            e4.z = __expf(sj.z - m0); e4.w = __expf(sj.w - m0);                 \
            f4.x = __expf(0.2f * (sj.x - m0)); f4.y = __expf(0.2f * (sj.y - m0)); \
            f4.z = __expf(0.2f * (sj.z - m0)); f4.w = __expf(0.2f * (sj.w - m0)); \
        }
#define ADJ_LOAD(DA, DB, DC, DD, J0)                                            \
        {                                                                       \
            DA = *(const int4*)(adjb + (size_t)(0 * 16 + trh) * N_NODES + (J0)); \
            DB = *(const int4*)(adjb + (size_t)(1 * 16 + trh) * N_NODES + (J0)); \
            DC = *(const int4*)(adjb + (size_t)(2 * 16 + trh) * N_NODES + (J0)); \
            DD = *(const int4*)(adjb + (size_t)(3 * 16 + trh) * N_NODES + (J0)); \
        }
#define BF_LOAD(B0, B1, B2, B3, T)                                              \
        {                                                                       \
            const unsigned short* p = bf_base + ((size_t)(T) << 12);            \
            B0 = *(const short8*)(p);                                           \
            B1 = *(const short8*)(p + 512);                                     \
            B2 = *(const short8*)(p + 1024);                                    \
            B3 = *(const short8*)(p + 1536);                                    \
        }

        int T0 = jb * 16;
        SJ_LOAD(jstart)
        BF_LOAD(Bc0, Bc1, Bc2, Bc3, T0)
        ADJ_LOAD(cA, cB, cC, cD, jstart)
        ADJ_LOAD(nA, nB_, nC, nD, jstart + 128)
        EF_GEN()
        W_GEN(0, cA, l0, wA)
        W_GEN(1, cB, l1, wA)
        W_GEN(2, cC, l2, wA)
        W_GEN(3, cD, l3, wA)
        cA = nA; cB = nB_; cC = nC; cD = nD;

        unsigned short* wcur = wA;
        unsigned short* wnxt = wB;
        for (int jt = 0; jt < 16; ++jt) {
            __syncthreads();
            if (jt < 15) {
                SJ_LOAD(jstart + (jt + 1) * 128)
                BF_LOAD(Bn0, Bn1, Bn2, Bn3, T0 + jt + 1)
            }
            if (jt < 14) {
                ADJ_LOAD(nA, nB_, nC, nD, jstart + (jt + 2) * 128)
            }
            {
                const char* wb = (const char*)wcur;
                short8 a0 = *(const short8*)(wb + ((a_base + 0 * 64 + grp * 16) ^ aswz));
                acc1 = __builtin_amdgcn_mfma_f32_16x16x32_bf16(a0, Bc0, acc1, 0, 0, 0);
                short8 a1 = *(const short8*)(wb + ((a_base + 1 * 64 + grp * 16) ^ aswz));
                acc1 = __builtin_amdgcn_mfma_f32_16x16x32_bf16(a1, Bc1, acc1, 0, 0, 0);
                short8 a2 = *(const short8*)(wb + ((a_base + 2 * 64 + grp * 16) ^ aswz));
                acc1 = __builtin_amdgcn_mfma_f32_16x16x32_bf16(a2, Bc2, acc1, 0, 0, 0);
                short8 a3 = *(const short8*)(wb + ((a_base + 3 * 64 + grp * 16) ^ aswz));
                acc1 = __builtin_amdgcn_mfma_f32_16x16x32_bf16(a3, Bc3, acc1, 0, 0, 0);
            }
            if (jt < 15) {
                EF_GEN()
                W_GEN(0, cA, l0, wnxt)
                W_GEN(1, cB, l1, wnxt)
                W_GEN(2, cC, l2, wnxt)
                W_GEN(3, cD, l3, wnxt)
                Bc0 = Bn0; Bc1 = Bn1; Bc2 = Bn2; Bc3 = Bn3;
                if (jt < 14) { cA = nA; cB = nB_; cC = nC; cD = nD; }
            }
            unsigned short* t_ = wcur; wcur = wnxt; wnxt = t_;
        }
#undef W_GEN
#undef SJ_LOAD
#undef EF_GEN
#undef ADJ_LOAD
#undef BF_LOAD

#pragma unroll
        for (int reg = 0; reg < 4; ++reg) {
            int grow = row0 + rg * 16 + grp * 4 + reg;
            num1[((size_t)jb * N_NODES + grow) * 32 + hg * 16 + (lane & 15)] = acc1[reg];
        }
#define DEN(KK, DD)                                                             \
        {                                                                       \
            float d = DD;                                                       \
            d += __shfl_xor(d, 1);                                              \
            d += __shfl_xor(d, 2);                                              \
            d += __shfl_xor(d, 4);                                              \
            d += __shfl_xor(d, 8);                                              \
            d += __shfl_xor(d, 16);                                             \
            if ((tid & 31) == 0) {                                              \
                int rr = KK * 16 + trh;                                         \
                den1[(size_t)jb * N_NODES + row0 + rr] = d;                     \
            }                                                                   \
        }
        DEN(0, l0)
        DEN(1, l1)
        DEN(2, l2)
        DEN(3, l3)
#undef DEN
    }
    gsync(cnt, 3 * NB);

    // ================= Phase E: z1/z2 + semantic score partials ============
    {
        float* zl1 = (float*)smem;                 // 512 f
        float* zl2 = (float*)(smem + 2048);        // 512 f
        float* rowsum = (float*)(smem + 4096);     // 16 f
        int row = r0 + r;

        float n1 = 0.f, d1 = 0.f;
#pragma unroll
        for (int j = 0; j < 4; ++j) {
            n1 += num1[((size_t)j * N_NODES + row) * 32 + h];
            d1 += den1[(size_t)j * N_NODES + row];
        }
        z1v = sigmoidf_(d1 > 0.f ? n1 / d1 : 0.f);

        int bt = (int)roundf((-sv2 - lo) * invw);
        bt = min(max(bt, 0), KB);
        float u = sv2 + m1;
        float g1 = u >= 0.f ? 1.f : __expf(0.8f * u);
        float g2 = u >= 0.f ? __expf(-0.8f * u) : 1.f;
#define GATHER(CH, B) ((B) >= KB ? 0.f : Sc[(size_t)(CH) * KB + (B)])
        float SufE  = GATHER(h, bt);
        float SufF  = GATHER(32 + h, bt);
        float TotF  = GATHER(32 + h, 0);
        float SufEs = GATHER(64, bt);
        float SufFs = GATHER(65, bt);
        float TotFs = GATHER(65, 0);
#undef GATHER
        float num2 = g1 * SufE + g2 * (TotF - SufF);
        float den2 = g1 * SufEs + g2 * (TotFs - SufFs);
        z2v = sigmoidf_(num2 / fmaxf(den2, 1e-30f));

        zl1[tid] = z1v;
        zl2[tid] = z2v;
        __syncthreads();

        const float* wr = Wsw + h * H;
        for (int p = 0; p < 2; ++p) {
            const float* zl = p ? zl2 : zl1;
            const float* zr = zl + r * H;
            float d = 0.f;
#pragma unroll
            for (int k = 0; k < H; ++k) d += zr[k] * wr[k];
            float val = tanh_fast(d + Wsb[h] + bsem[h]) * q[h];
#pragma unroll
            for (int m = 16; m >= 1; m >>= 1) val += __shfl_xor(val, m);
            if (h == 0) rowsum[r] = val;
            __syncthreads();
            if (tid == 0) {
                float s = 0.f;
#pragma unroll
                for (int i = 0; i < 16; ++i) s += rowsum[i];
                atomicAdd(&wsum[p], s);
            }
            __syncthreads();
        }
    }
    gsync(cnt, 4 * NB);

    // ================= Phase F: beta + z_final + logits ====================
    {
        float w0 = wsum[0] / (float)N_NODES;
        float w1 = wsum[1] / (float)N_NODES;
        float mx = fmaxf(w0, w1);
        float e0 = __expf(w0 - mx), e1 = __expf(w1 - mx);
        float inv = 1.f / (e0 + e1);
        float be0 = e0 * inv, be1 = e1 * inv;

        int grow = r0 + r;
        float zf = be0 * z1v + be1 * z2v;
        out[(size_t)grow * H + h] = zf;
        float p0 = zf * clsw[h];
        float p1 = zf * clsw[H + h];
#pragma unroll
        for (int m = 16; m >= 1; m >>= 1) { p0 += __shfl_xor(p0, m); p1 += __shfl_xor(p1, m); }
        if (h == 0) {
            out[(size_t)N_NODES * H + (size_t)grow * 2]     = p0 + clsb[0];
            out[(size_t)N_NODES * H + (size_t)grow * 2 + 1] = p1 + clsb[1];
        }
    }
}

extern "C" void kernel_launch(void* const* d_in, const int* in_sizes, int n_in,
                              void* d_out, int out_size, void* d_ws, size_t ws_size,
                              hipStream_t stream)
{
    const float* x    = (const float*)d_in[0];
    const float* W1   = (const float*)d_in[1];
    const float* b1   = (const float*)d_in[2];
    const float* a1   = (const float*)d_in[3];
    const float* W2   = (const float*)d_in[4];
    const float* b2   = (const float*)d_in[5];
    const float* a2   = (const float*)d_in[6];
    const float* q    = (const float*)d_in[7];
    const float* Wsw  = (const float*)d_in[8];
    const float* Wsb  = (const float*)d_in[9];
    const float* bsem = (const float*)d_in[10];
    const float* clsw = (const float*)d_in[11];
    const float* clsb = (const float*)d_in[12];
    const int*   adj  = (const int*)d_in[13];
    // d_in[14] = mg_adj : unused

    // Workspace layout in FLOAT units.
    float* ws = (float*)d_ws;
    unsigned* cnt        = (unsigned*)ws;                     // 64 f reserved
    unsigned short* WhTf = (unsigned short*)(ws + 64);        // 131072 f (bf16 frag)
    float* s1g   = ws + 64 + 131072;                          // 8192
    float* maxp1 = s1g + N_NODES;                             // 512
    float* maxp2 = maxp1 + NB;                                // 512
    float* minp2 = maxp2 + NB;                                // 512
    float* wsum  = minp2 + NB;                                // 64 reserved
    float* num1  = wsum + 64;                                 // 4*8192*32
    float* den1  = num1 + 4 * N_NODES * 32;                   // 4*8192
    float* Sc    = den1 + 4 * N_NODES;                        // 66*8192
    // total ~= 1.76M floats ~= 7 MB

    hipMemsetAsync(cnt, 0, sizeof(unsigned), stream);
    hipLaunchKernelGGL(han_mega, dim3(NB), dim3(BT), 0, stream,
                       x, W1, b1, a1, W2, b2, a2, q, Wsw, Wsb, bsem, clsw, clsb, adj,
                       cnt, WhTf, s1g, maxp1, maxp2, minp2, wsum,
                       num1, den1, Sc, (float*)d_out);
}